// Round 8
// baseline (206.213 us; speedup 1.0000x reference)
//
#include <hip/hip_runtime.h>
#include <stdint.h>

#define BATCH 4
#define SEQ 2048
#define NX 1024
#define NHEAD 16
#define HDIM 64
#define NTOK (BATCH * SEQ)   // 8192
#define QKV_LD (3 * NX)      // 3072

typedef __bf16 bf16_t;
typedef __bf16 bf16x8 __attribute__((ext_vector_type(8)));
typedef __bf16 bf16x4 __attribute__((ext_vector_type(4)));
typedef float  f32x4  __attribute__((ext_vector_type(4)));

#define GLOAD_LDS16(g, l) __builtin_amdgcn_global_load_lds( \
    (const __attribute__((address_space(1))) void*)(g),     \
    (__attribute__((address_space(3))) void*)(l), 16, 0, 0)

#define MFMA16(a, b, c) __builtin_amdgcn_mfma_f32_16x16x32_bf16((a), (b), (c), 0, 0, 0)

#define WAIT_VM4_BAR() do { \
    asm volatile("s_waitcnt vmcnt(4) lgkmcnt(0)" ::: "memory"); \
    __builtin_amdgcn_s_barrier(); } while (0)
#define WAIT_VM0_BAR() do { \
    asm volatile("s_waitcnt vmcnt(0) lgkmcnt(0)" ::: "memory"); \
    __builtin_amdgcn_s_barrier(); } while (0)

// ---------------- cast f32 -> bf16 (vectorized) ----------------
__global__ __launch_bounds__(256) void k_cast_bf16(const float* __restrict__ in,
                                                   bf16_t* __restrict__ out, int n4) {
  int stride = gridDim.x * blockDim.x;
  for (int i = blockIdx.x * blockDim.x + threadIdx.x; i < n4; i += stride) {
    f32x4 v = ((const f32x4*)in)[i];
    bf16x4 o;
    o[0] = (bf16_t)v[0]; o[1] = (bf16_t)v[1];
    o[2] = (bf16_t)v[2]; o[3] = (bf16_t)v[3];
    ((bf16x4*)out)[i] = o;
  }
}

// ---------------- transpose + cast: in[K][N] f32 -> out[N][K] bf16 ----------------
__global__ __launch_bounds__(256) void k_transpose_cast(const float* __restrict__ in,
                                                        bf16_t* __restrict__ out,
                                                        int K, int N) {
  __shared__ float tile[32][33];
  const int kb = blockIdx.x * 32, nb = blockIdx.y * 32;
  const int tx = threadIdx.x & 31;
  const int ty = (threadIdx.x >> 5) * 4;
#pragma unroll
  for (int i = 0; i < 4; i++)
    tile[ty + i][tx] = in[(size_t)(kb + ty + i) * N + nb + tx];
  __syncthreads();
#pragma unroll
  for (int i = 0; i < 4; i++)
    out[(size_t)(nb + ty + i) * K + kb + tx] = (bf16_t)tile[tx][ty + i];
}

// ---------------- V transpose: qkv V-part [s][d] -> vt[bh][d][s] bf16 ----------------
__global__ __launch_bounds__(256) void k_vtrans(const bf16_t* __restrict__ qkv,
                                                bf16_t* __restrict__ vt) {
  __shared__ bf16_t tile[32][33];
  const int s0 = blockIdx.x * 32;
  const int d0 = blockIdx.y * 32;
  const int bh = blockIdx.z;
  const int b = bh >> 4, h = bh & 15;
  const bf16_t* src = qkv + (size_t)b * SEQ * QKV_LD + 2 * NX + h * HDIM;
  const int tx = threadIdx.x & 31;
  const int ty = (threadIdx.x >> 5) * 4;
#pragma unroll
  for (int i = 0; i < 4; i++)
    tile[ty + i][tx] = src[(size_t)(s0 + ty + i) * QKV_LD + d0 + tx];
  __syncthreads();
  bf16_t* dst = vt + (size_t)bh * HDIM * SEQ;
#pragma unroll
  for (int i = 0; i < 4; i++)
    dst[(size_t)(d0 + ty + i) * SEQ + s0 + tx] = tile[tx][ty + i];
}

// ---------------- 256x256 8-phase GEMM (QKV): C = A * Bt^T + bias, bf16 out ----
// BM=BN=256, BK=64, 8 waves (2 Mq x 4 Nq sub-split per 128x128 quadrant).
// LDS 128 KB: A/B x 2 bufs x [256][64]. T2 chunk-swizzle (slot ^= row&3, pre-
// swizzled global source + swizzled ds_read). T3/T4: per-phase half-tile stage,
// counted vmcnt(6) only at tile boundaries. T5: setprio around MFMA clusters.
// Stagger (tile t): p0 stages B1(t+1) [other buf], p1 stages A0(t+2),
// p3 stages B0(t+2)+A1(t+2); every staged region died a trailing-barrier earlier.
#define PHASE8(MH, NH, READA, STAGE, ENDWAIT) do {                              \
    if (READA) {                                                                \
      _Pragma("unroll") for (int mf = 0; mf < 4; mf++)                          \
      _Pragma("unroll") for (int ks = 0; ks < 2; ks++)                          \
        af[mf][ks] = *(const bf16x8*)&lsA[cur][((MH)*128 + wq*64 + mf*16 + fr)*64 \
                         + (((ks*4 + g2) ^ (fr & 3)) << 3)];                    \
    }                                                                           \
    bf16x8 bfr[2][2];                                                           \
    _Pragma("unroll") for (int nf = 0; nf < 2; nf++)                            \
    _Pragma("unroll") for (int ks = 0; ks < 2; ks++)                            \
      bfr[nf][ks] = *(const bf16x8*)&lsB[cur][((NH)*128 + wn*32 + nf*16 + fr)*64 \
                         + (((ks*4 + g2) ^ (fr & 3)) << 3)];                    \
    STAGE;                                                                      \
    __builtin_amdgcn_s_barrier();                                               \
    asm volatile("s_waitcnt lgkmcnt(0)" ::: "memory");                          \
    __builtin_amdgcn_sched_barrier(0);                                          \
    __builtin_amdgcn_s_setprio(1);                                              \
    _Pragma("unroll") for (int mf = 0; mf < 4; mf++)                            \
    _Pragma("unroll") for (int nf = 0; nf < 2; nf++)                            \
    _Pragma("unroll") for (int ks = 0; ks < 2; ks++)                            \
      acc[MH][NH][mf][nf] = MFMA16(af[mf][ks], bfr[nf][ks], acc[MH][NH][mf][nf]); \
    __builtin_amdgcn_s_setprio(0);                                              \
    ENDWAIT;                                                                    \
    __builtin_amdgcn_s_barrier();                                               \
  } while (0)

__global__ __launch_bounds__(512, 2) void k_gemm8(const bf16_t* __restrict__ A,
                                                  const bf16_t* __restrict__ Bt,
                                                  const float* __restrict__ bias,
                                                  bf16_t* __restrict__ Cout,
                                                  int M, int N, int K) {
  __shared__ __align__(16) bf16_t lsA[2][256 * 64];
  __shared__ __align__(16) bf16_t lsB[2][256 * 64];
  const int tid = threadIdx.x, lane = tid & 63, wid = tid >> 6;
  const int wq = wid >> 2;         // 0..1 : M sub-row within a quadrant
  const int wn = wid & 3;          // 0..3 : N sub-col within a quadrant
  const int m0 = blockIdx.x * 256, n0 = blockIdx.y * 256;
  const int fr = lane & 15, g2 = lane >> 4;

  // staging: 16 chunks of 8 rows per half-tile; wave w covers chunks 2w, 2w+1.
  const int srow8 = lane >> 3, sslot = lane & 7;
  const int sswz = (sslot ^ (srow8 & 3)) << 3;   // inverse-swizzled source slot

  const bf16_t* Ab = A + (size_t)m0 * K;
  const bf16_t* Bb = Bt + (size_t)n0 * K;

  auto stA = [&](int buf, int half, int kt) {
#pragma unroll
    for (int i = 0; i < 2; i++) {
      const int rl = half * 128 + (wid * 2 + i) * 8 + srow8;
      GLOAD_LDS16(Ab + (size_t)rl * K + kt * 64 + sswz,
                  &lsA[buf][(half * 128 + (wid * 2 + i) * 8) * 64]);
    }
  };
  auto stB = [&](int buf, int half, int kt) {
#pragma unroll
    for (int i = 0; i < 2; i++) {
      const int rl = half * 128 + (wid * 2 + i) * 8 + srow8;
      GLOAD_LDS16(Bb + (size_t)rl * K + kt * 64 + sswz,
                  &lsB[buf][(half * 128 + (wid * 2 + i) * 8) * 64]);
    }
  };

  f32x4 acc[2][2][4][2];
#pragma unroll
  for (int a = 0; a < 2; a++)
#pragma unroll
    for (int b2 = 0; b2 < 2; b2++)
#pragma unroll
      for (int c = 0; c < 4; c++)
#pragma unroll
        for (int d = 0; d < 2; d++) acc[a][b2][c][d] = (f32x4){0.f, 0.f, 0.f, 0.f};

  const int NT = K >> 6;   // 16 K-tiles of 64
  // prologue: tile0 complete + tile1 {A0,B0,A1}; B1(1) arrives at t0 p0.
  stA(0, 0, 0); stB(0, 0, 0); stA(0, 1, 0); stB(0, 1, 0);
  stA(1, 0, 1); stB(1, 0, 1); stA(1, 1, 1);
  asm volatile("s_waitcnt vmcnt(6)" ::: "memory");   // tile0's 8 loads landed
  __builtin_amdgcn_s_barrier();

  bf16x8 af[4][2];
  for (int t = 0; t < NT; t++) {
    const int cur = t & 1, nxt = cur ^ 1;
    // p0: quadrant (M0,N0), read A-half0; stage B1(t+1) into other buf
    PHASE8(0, 0, 1, { if (t + 1 < NT) stB(nxt, 1, t + 1); }, {});
    // p1: quadrant (M0,N1), reuse A; stage A0(t+2) (region died at p0)
    PHASE8(0, 1, 0, { if (t + 2 < NT) stA(cur, 0, t + 2); }, {});
    // p2: quadrant (M1,N0), read A-half1
    PHASE8(1, 0, 1, {}, {});
    // p3: quadrant (M1,N1); stage B0(t+2)+A1(t+2) (died at p2); boundary wait
    PHASE8(1, 1, 0,
           { if (t + 2 < NT) { stB(cur, 0, t + 2); stA(cur, 1, t + 2); } },
           { if (t < NT - 1) {
               if (t == NT - 2) asm volatile("s_waitcnt vmcnt(0)" ::: "memory");
               else             asm volatile("s_waitcnt vmcnt(6)" ::: "memory");
             } });
  }

  // epilogue: C/D layout col=lane&15, row=(lane>>4)*4+reg
  const int col = lane & 15, rb = (lane >> 4) * 4;
#pragma unroll
  for (int mh = 0; mh < 2; mh++)
#pragma unroll
    for (int nh = 0; nh < 2; nh++)
#pragma unroll
      for (int mf = 0; mf < 4; mf++)
#pragma unroll
        for (int nf = 0; nf < 2; nf++) {
          const int gm = m0 + mh * 128 + wq * 64 + mf * 16 + rb;
          const int gn = n0 + nh * 128 + wn * 32 + nf * 16 + col;
          const float bv = bias[gn];
#pragma unroll
          for (int r = 0; r < 4; r++)
            Cout[(size_t)(gm + r) * N + gn] = (bf16_t)(acc[mh][nh][mf][nf][r] + bv);
        }
}

// ---------------- GEMM (proj): C[M][N] = A[M][K] * Bt[N][K]^T + bias ----------
// 128x128 tile, BK=32, 4 waves 2x2; double-buffered LDS, issue-early staging.
template <int OUT_BF16>
__global__ __launch_bounds__(256) void k_gemm_bt(const bf16_t* __restrict__ A,
                                                 const bf16_t* __restrict__ Bt,
                                                 const float* __restrict__ bias,
                                                 void* __restrict__ Cout,
                                                 int M, int N, int K) {
  __shared__ __align__(16) bf16_t lsA[2][128 * 32];
  __shared__ __align__(16) bf16_t lsB[2][128 * 32];
  const int tid  = threadIdx.x;
  const int lane = tid & 63;
  const int wid  = tid >> 6;
  const int wr   = wid >> 1, wc = wid & 1;
  const int m0 = blockIdx.x * 128, n0 = blockIdx.y * 128;

  const int srow = tid >> 2;
  const int scol = (tid & 3) * 8;
  const bf16_t* Ap = A  + (size_t)(m0 + srow) * K + scol;
  const bf16_t* Bp = Bt + (size_t)(n0 + srow) * K + scol;
  const int wbase = (tid & ~63) * 8;

  f32x4 acc[4][4];
#pragma unroll
  for (int i = 0; i < 4; i++)
#pragma unroll
    for (int j = 0; j < 4; j++) acc[i][j] = (f32x4){0.f, 0.f, 0.f, 0.f};

  const int fr = lane & 15;
  const int kb = (lane >> 4) * 8;

  auto stage = [&](int buf, int k0) {
    GLOAD_LDS16(Ap + k0,                  &lsA[buf][wbase]);
    GLOAD_LDS16(Ap + (size_t)64 * K + k0, &lsA[buf][2048 + wbase]);
    GLOAD_LDS16(Bp + k0,                  &lsB[buf][wbase]);
    GLOAD_LDS16(Bp + (size_t)64 * K + k0, &lsB[buf][2048 + wbase]);
  };

  stage(0, 0);
  __syncthreads();
  const int nk = K >> 5;
  for (int kt = 0; kt < nk; kt++) {
    const int cur = kt & 1;
    if (kt + 1 < nk) stage(cur ^ 1, (kt + 1) * 32);
    bf16x8 af[4], bfr[4];
#pragma unroll
    for (int mf = 0; mf < 4; mf++)
      af[mf] = *(const bf16x8*)&lsA[cur][(wr * 64 + mf * 16 + fr) * 32 + kb];
#pragma unroll
    for (int nf = 0; nf < 4; nf++)
      bfr[nf] = *(const bf16x8*)&lsB[cur][(wc * 64 + nf * 16 + fr) * 32 + kb];
#pragma unroll
    for (int mf = 0; mf < 4; mf++)
#pragma unroll
      for (int nf = 0; nf < 4; nf++)
        acc[mf][nf] = MFMA16(af[mf], bfr[nf], acc[mf][nf]);
    __syncthreads();
  }

  const int col = lane & 15, rb = (lane >> 4) * 4;
#pragma unroll
  for (int mf = 0; mf < 4; mf++) {
#pragma unroll
    for (int nf = 0; nf < 4; nf++) {
      const int gm = m0 + wr * 64 + mf * 16 + rb;
      const int gn = n0 + wc * 64 + nf * 16 + col;
      const float bv = bias[gn];
#pragma unroll
      for (int r = 0; r < 4; r++) {
        float v = acc[mf][nf][r] + bv;
        if (OUT_BF16)
          ((bf16_t*)Cout)[(size_t)(gm + r) * N + gn] = (bf16_t)v;
        else
          ((float*)Cout)[(size_t)(gm + r) * N + gn] = v;
      }
    }
  }
}

// ---------------- causal flash attention (round-5 best: 82.8 us) ----------------
// 4 waves/block, 64 q-rows per wave, KVBLK=64; 3-buffer LDS, depth-2 prefetch,
// counted vmcnt + raw barrier; swapped QK^T + permuted K rows; no-max softmax.
__global__ __launch_bounds__(256, 2) void k_attn(const bf16_t* __restrict__ qkv,
                                                 const bf16_t* __restrict__ vt,
                                                 bf16_t* __restrict__ attout) {
  __shared__ __align__(16) bf16_t lsK[3][64 * 64];
  __shared__ __align__(16) bf16_t lsV[3][64 * 64];
  const int tid = threadIdx.x, lane = tid & 63, w = tid >> 6;
  const int blk = blockIdx.x;
  const int xcd = blk & 7, idx = blk >> 3;
  const int bh  = xcd * 8 + (idx & 7);
  const int qsb = 7 - (idx >> 3);
  const int b = bh >> 4, h = bh & 15;
  const bf16_t* Qb  = qkv + (size_t)b * SEQ * QKV_LD + h * HDIM;
  const bf16_t* Kb  = Qb + NX;
  const bf16_t* Vtb = vt + (size_t)bh * HDIM * SEQ;

  const int fr = lane & 15, g2 = lane >> 4;
  const int kb8 = g2 * 8;
  const int permA = (fr & 3) + 8 * (fr >> 2);

  auto stage = [&](int buf, int kv0) {
#pragma unroll
    for (int s = 0; s < 2; s++) {
      const int i = w * 128 + s * 64 + lane;
      const int row = i >> 3, slot = i & 7;
      const int sk = (row & 3) | (((row >> 3) & 1) << 2);
      GLOAD_LDS16(Kb + (size_t)(kv0 + row) * QKV_LD + ((slot ^ sk) << 3),
                  &lsK[buf][(w * 128 + s * 64) * 8]);
      GLOAD_LDS16(Vtb + (size_t)row * SEQ + kv0 + ((slot ^ (row & 7)) << 3),
                  &lsV[buf][(w * 128 + s * 64) * 8]);
    }
  };

  const int wb = qsb * 256 + w * 64;
  const int kv_last = wb;
  const int nst = qsb * 4 + 4;

  bf16x8 bq[4][2];
#pragma unroll
  for (int g = 0; g < 4; g++)
#pragma unroll
    for (int kf = 0; kf < 2; kf++) {
      bf16x8 t = *(const bf16x8*)&Qb[(size_t)(wb + g * 16 + fr) * QKV_LD + kf * 32 + kb8];
#pragma unroll
      for (int jj = 0; jj < 8; jj++) t[jj] = (bf16_t)((float)t[jj] * 0.1803368801f);
      bq[g][kf] = t;
    }

  float l_run[4] = {0.f, 0.f, 0.f, 0.f};
  f32x4 o[4][4];
#pragma unroll
  for (int g = 0; g < 4; g++)
#pragma unroll
    for (int d = 0; d < 4; d++) o[g][d] = (f32x4){0.f, 0.f, 0.f, 0.f};

  stage(0, 0);
  stage(1, 64);
  asm volatile("s_waitcnt vmcnt(4)" ::: "memory");
  __builtin_amdgcn_s_barrier();

  for (int st = 0; st < nst; st++) {
    const int kv0 = st * 64;
    const int cur = st % 3;
    if (st + 2 < nst) stage((st + 2) % 3, (st + 2) * 64);
    if (kv0 <= kv_last) {
      bf16x8 ak[2][2][2];
#pragma unroll
      for (int sub = 0; sub < 2; sub++)
#pragma unroll
        for (int ab = 0; ab < 2; ab++)
#pragma unroll
          for (int kf = 0; kf < 2; kf++) {
            const int row = sub * 32 + ab * 4 + permA;
            const int sk = (row & 3) | (((row >> 3) & 1) << 2);
            const int c = kf * 4 + g2;
            ak[sub][ab][kf] = *(const bf16x8*)&lsK[cur][row * 64 + ((c ^ sk) << 3)];
          }
      bf16x8 vbf[4][2];
#pragma unroll
      for (int df = 0; df < 4; df++)
#pragma unroll
        for (int hh = 0; hh < 2; hh++) {
          const int row = df * 16 + fr;
          const int c = hh * 4 + g2;
          vbf[df][hh] = *(const bf16x8*)&lsV[cur][row * 64 + ((c ^ (row & 7)) << 3)];
        }
      const int masked = (kv0 == kv_last);
#pragma unroll
      for (int g = 0; g < 4; g++) {
        f32x4 sAB[2][2];
        __builtin_amdgcn_s_setprio(1);
#pragma unroll
        for (int sub = 0; sub < 2; sub++)
#pragma unroll
          for (int ab = 0; ab < 2; ab++) {
            f32x4 s0 = (f32x4){0.f, 0.f, 0.f, 0.f};
            s0 = MFMA16(ak[sub][ab][0], bq[g][0], s0);
            s0 = MFMA16(ak[sub][ab][1], bq[g][1], s0);
            sAB[sub][ab] = s0;
          }
        __builtin_amdgcn_s_setprio(0);
        float sv[16];
#pragma unroll
        for (int sub = 0; sub < 2; sub++)
#pragma unroll
          for (int r = 0; r < 4; r++) {
            sv[sub * 8 + r]     = sAB[sub][0][r];
            sv[sub * 8 + 4 + r] = sAB[sub][1][r];
          }
        if (masked) {
          const int q_abs = wb + g * 16 + fr;
#pragma unroll
          for (int sub = 0; sub < 2; sub++)
#pragma unroll
            for (int r = 0; r < 4; r++) {
              if (kv0 + sub * 32 + g2 * 8 + r     > q_abs) sv[sub * 8 + r]     = -1e30f;
              if (kv0 + sub * 32 + g2 * 8 + 4 + r > q_abs) sv[sub * 8 + 4 + r] = -1e30f;
            }
        }
        float tsum = 0.f;
        bf16_t pb[16];
#pragma unroll
        for (int jj = 0; jj < 16; jj++) {
          float pv = exp2f(sv[jj]);
          tsum += pv;
          pb[jj] = (bf16_t)pv;
        }
        l_run[g] += tsum;
        bf16x8 pa0, pa1;
#pragma unroll
        for (int jj = 0; jj < 8; jj++) { pa0[jj] = pb[jj]; pa1[jj] = pb[8 + jj]; }
        __builtin_amdgcn_s_setprio(1);
#pragma unroll
        for (int df = 0; df < 4; df++) {
          o[g][df] = MFMA16(pa0, vbf[df][0], o[g][df]);
          o[g][df] = MFMA16(pa1, vbf[df][1], o[g][df]);
        }
        __builtin_amdgcn_s_setprio(0);
      }
    }
    if (st + 1 < nst) {
      if (st + 2 < nst) WAIT_VM4_BAR(); else WAIT_VM0_BAR();
    }
  }

#pragma unroll
  for (int g = 0; g < 4; g++) {
    float lt = l_run[g];
    lt += __shfl_xor(lt, 16);
    lt += __shfl_xor(lt, 32);
    const float inv = 1.f / lt;
#pragma unroll
    for (int r = 0; r < 4; r++) {
      const float iv = __shfl(inv, g2 * 4 + r);
      const int tok = b * SEQ + wb + g * 16 + g2 * 4 + r;
#pragma unroll
      for (int df = 0; df < 4; df++)
        attout[(size_t)tok * NX + h * HDIM + df * 16 + fr] = (bf16_t)(o[g][df][r] * iv);
    }
  }
}

// ---------------- launch ----------------
extern "C" void kernel_launch(void* const* d_in, const int* in_sizes, int n_in,
                              void* d_out, int out_size, void* d_ws, size_t ws_size,
                              hipStream_t stream) {
  const float* x      = (const float*)d_in[0];
  const float* w_attn = (const float*)d_in[1];
  const float* b_attn = (const float*)d_in[2];
  const float* w_proj = (const float*)d_in[3];
  const float* b_proj = (const float*)d_in[4];

  char* ws = (char*)d_ws;
  bf16_t* xb  = (bf16_t*)ws;                   // [0,16) MiB, reused as att
  bf16_t* qkv = (bf16_t*)(ws + (16u << 20));   // [16,64) MiB
  bf16_t* wab = (bf16_t*)(ws + (64u << 20));   // [64,70) MiB, dead after QKV GEMM
  bf16_t* vt  = (bf16_t*)(ws + (64u << 20));   // [64,80) MiB (reuses wab region)
  bf16_t* wpb = (bf16_t*)(ws + (80u << 20));   // [80,82) MiB
  bf16_t* att = xb;

  k_cast_bf16<<<2048, 256, 0, stream>>>(x, xb, NTOK * NX / 4);
  k_transpose_cast<<<dim3(NX / 32, (3 * NX) / 32), 256, 0, stream>>>(w_attn, wab, NX, 3 * NX);
  k_gemm8<<<dim3(NTOK / 256, (3 * NX) / 256), 512, 0, stream>>>(
      xb, wab, b_attn, qkv, NTOK, 3 * NX, NX);
  // xb and wab dead from here
  k_vtrans<<<dim3(SEQ / 32, HDIM / 32, BATCH * NHEAD), 256, 0, stream>>>(qkv, vt);
  k_transpose_cast<<<dim3(NX / 32, NX / 32), 256, 0, stream>>>(w_proj, wpb, NX, NX);
  k_attn<<<BATCH * NHEAD * 8, 256, 0, stream>>>(qkv, vt, att);
  k_gemm_bt<0><<<dim3(NTOK / 128, NX / 128), 256, 0, stream>>>(
      att, wpb, b_proj, d_out, NTOK, NX, NX);
}

// Round 9
// 198.573 us; speedup vs baseline: 1.0385x; 1.0385x over previous
//
#include <hip/hip_runtime.h>
#include <stdint.h>

#define BATCH 4
#define SEQ 2048
#define NX 1024
#define NHEAD 16
#define HDIM 64
#define NTOK (BATCH * SEQ)   // 8192
#define QKV_LD (3 * NX)      // 3072

typedef __bf16 bf16_t;
typedef __bf16 bf16x8 __attribute__((ext_vector_type(8)));
typedef __bf16 bf16x4 __attribute__((ext_vector_type(4)));
typedef float  f32x4  __attribute__((ext_vector_type(4)));

#define GLOAD_LDS16(g, l) __builtin_amdgcn_global_load_lds( \
    (const __attribute__((address_space(1))) void*)(g),     \
    (__attribute__((address_space(3))) void*)(l), 16, 0, 0)

#define MFMA16(a, b, c) __builtin_amdgcn_mfma_f32_16x16x32_bf16((a), (b), (c), 0, 0, 0)

#define WAIT_VM4_BAR() do { \
    asm volatile("s_waitcnt vmcnt(4) lgkmcnt(0)" ::: "memory"); \
    __builtin_amdgcn_s_barrier(); } while (0)
#define WAIT_VM0_BAR() do { \
    asm volatile("s_waitcnt vmcnt(0) lgkmcnt(0)" ::: "memory"); \
    __builtin_amdgcn_s_barrier(); } while (0)

// ---------------- cast f32 -> bf16 (vectorized) ----------------
__global__ __launch_bounds__(256) void k_cast_bf16(const float* __restrict__ in,
                                                   bf16_t* __restrict__ out, int n4) {
  int stride = gridDim.x * blockDim.x;
  for (int i = blockIdx.x * blockDim.x + threadIdx.x; i < n4; i += stride) {
    f32x4 v = ((const f32x4*)in)[i];
    bf16x4 o;
    o[0] = (bf16_t)v[0]; o[1] = (bf16_t)v[1];
    o[2] = (bf16_t)v[2]; o[3] = (bf16_t)v[3];
    ((bf16x4*)out)[i] = o;
  }
}

// ---------------- transpose + cast: in[K][N] f32 -> out[N][K] bf16 ----------------
__global__ __launch_bounds__(256) void k_transpose_cast(const float* __restrict__ in,
                                                        bf16_t* __restrict__ out,
                                                        int K, int N) {
  __shared__ float tile[32][33];
  const int kb = blockIdx.x * 32, nb = blockIdx.y * 32;
  const int tx = threadIdx.x & 31;
  const int ty = (threadIdx.x >> 5) * 4;
#pragma unroll
  for (int i = 0; i < 4; i++)
    tile[ty + i][tx] = in[(size_t)(kb + ty + i) * N + nb + tx];
  __syncthreads();
#pragma unroll
  for (int i = 0; i < 4; i++)
    out[(size_t)(nb + ty + i) * K + kb + tx] = (bf16_t)tile[tx][ty + i];
}

// ---------------- V transpose: qkv V-part [s][d] -> vt[bh][d][s] bf16 ----------------
__global__ __launch_bounds__(256) void k_vtrans(const bf16_t* __restrict__ qkv,
                                                bf16_t* __restrict__ vt) {
  __shared__ bf16_t tile[32][33];
  const int s0 = blockIdx.x * 32;
  const int d0 = blockIdx.y * 32;
  const int bh = blockIdx.z;
  const int b = bh >> 4, h = bh & 15;
  const bf16_t* src = qkv + (size_t)b * SEQ * QKV_LD + 2 * NX + h * HDIM;
  const int tx = threadIdx.x & 31;
  const int ty = (threadIdx.x >> 5) * 4;
#pragma unroll
  for (int i = 0; i < 4; i++)
    tile[ty + i][tx] = src[(size_t)(s0 + ty + i) * QKV_LD + d0 + tx];
  __syncthreads();
  bf16_t* dst = vt + (size_t)bh * HDIM * SEQ;
#pragma unroll
  for (int i = 0; i < 4; i++)
    dst[(size_t)(d0 + ty + i) * SEQ + s0 + tx] = tile[tx][ty + i];
}

// ---------------- 256x256 8-phase GEMM (QKV): C = A * Bt^T + bias, bf16 out ----
// BM=BN=256, BK=64, 8 waves. LDS 128 KB. T2 swizzle: FULL 3-bit involution
// (slot ^= row&7) -- the r8 2-bit version left bit2 of the slot fixed per
// ds_read (= ks), confining 64 lanes to 4 of 8 bank groups (6.3M conflicts).
// row&7 == fr&7 for all fragment rows (bases are multiples of 16/32).
// T3/T4: per-phase half-tile stage, counted vmcnt(6) at tile boundaries only.
#define PHASE8(MH, NH, READA, STAGE, ENDWAIT) do {                              \
    if (READA) {                                                                \
      _Pragma("unroll") for (int mf = 0; mf < 4; mf++)                          \
      _Pragma("unroll") for (int ks = 0; ks < 2; ks++)                          \
        af[mf][ks] = *(const bf16x8*)&lsA[cur][((MH)*128 + wq*64 + mf*16 + fr)*64 \
                         + (((ks*4 + g2) ^ (fr & 7)) << 3)];                    \
    }                                                                           \
    bf16x8 bfr[2][2];                                                           \
    _Pragma("unroll") for (int nf = 0; nf < 2; nf++)                            \
    _Pragma("unroll") for (int ks = 0; ks < 2; ks++)                            \
      bfr[nf][ks] = *(const bf16x8*)&lsB[cur][((NH)*128 + wn*32 + nf*16 + fr)*64 \
                         + (((ks*4 + g2) ^ (fr & 7)) << 3)];                    \
    STAGE;                                                                      \
    __builtin_amdgcn_s_barrier();                                               \
    asm volatile("s_waitcnt lgkmcnt(0)" ::: "memory");                          \
    __builtin_amdgcn_sched_barrier(0);                                          \
    __builtin_amdgcn_s_setprio(1);                                              \
    _Pragma("unroll") for (int mf = 0; mf < 4; mf++)                            \
    _Pragma("unroll") for (int nf = 0; nf < 2; nf++)                            \
    _Pragma("unroll") for (int ks = 0; ks < 2; ks++)                            \
      acc[MH][NH][mf][nf] = MFMA16(af[mf][ks], bfr[nf][ks], acc[MH][NH][mf][nf]); \
    __builtin_amdgcn_s_setprio(0);                                              \
    ENDWAIT;                                                                    \
    __builtin_amdgcn_s_barrier();                                               \
  } while (0)

__global__ __launch_bounds__(512, 2) void k_gemm8(const bf16_t* __restrict__ A,
                                                  const bf16_t* __restrict__ Bt,
                                                  const float* __restrict__ bias,
                                                  bf16_t* __restrict__ Cout,
                                                  int M, int N, int K) {
  __shared__ __align__(16) bf16_t lsA[2][256 * 64];
  __shared__ __align__(16) bf16_t lsB[2][256 * 64];
  const int tid = threadIdx.x, lane = tid & 63, wid = tid >> 6;
  const int wq = wid >> 2;         // 0..1 : M sub-row within a quadrant
  const int wn = wid & 3;          // 0..3 : N sub-col within a quadrant
  const int m0 = blockIdx.x * 256, n0 = blockIdx.y * 256;
  const int fr = lane & 15, g2 = lane >> 4;

  // staging: 16 chunks of 8 rows per half-tile; wave w covers chunks 2w, 2w+1.
  // linear LDS dest; inverse-swizzled global source slot (3-bit involution).
  const int srow8 = lane >> 3, sslot = lane & 7;
  const int sswz = (sslot ^ srow8) << 3;

  const bf16_t* Ab = A + (size_t)m0 * K;
  const bf16_t* Bb = Bt + (size_t)n0 * K;

  auto stA = [&](int buf, int half, int kt) {
#pragma unroll
    for (int i = 0; i < 2; i++) {
      const int rl = half * 128 + (wid * 2 + i) * 8 + srow8;
      GLOAD_LDS16(Ab + (size_t)rl * K + kt * 64 + sswz,
                  &lsA[buf][(half * 128 + (wid * 2 + i) * 8) * 64]);
    }
  };
  auto stB = [&](int buf, int half, int kt) {
#pragma unroll
    for (int i = 0; i < 2; i++) {
      const int rl = half * 128 + (wid * 2 + i) * 8 + srow8;
      GLOAD_LDS16(Bb + (size_t)rl * K + kt * 64 + sswz,
                  &lsB[buf][(half * 128 + (wid * 2 + i) * 8) * 64]);
    }
  };

  f32x4 acc[2][2][4][2];
#pragma unroll
  for (int a = 0; a < 2; a++)
#pragma unroll
    for (int b2 = 0; b2 < 2; b2++)
#pragma unroll
      for (int c = 0; c < 4; c++)
#pragma unroll
        for (int d = 0; d < 2; d++) acc[a][b2][c][d] = (f32x4){0.f, 0.f, 0.f, 0.f};

  const int NT = K >> 6;   // 16 K-tiles of 64
  // prologue: tile0 complete + tile1 {A0,B0,A1}; B1(1) arrives at t0 p0.
  stA(0, 0, 0); stB(0, 0, 0); stA(0, 1, 0); stB(0, 1, 0);
  stA(1, 0, 1); stB(1, 0, 1); stA(1, 1, 1);
  asm volatile("s_waitcnt vmcnt(6)" ::: "memory");   // tile0's 8 loads landed
  __builtin_amdgcn_s_barrier();

  bf16x8 af[4][2];
  for (int t = 0; t < NT; t++) {
    const int cur = t & 1, nxt = cur ^ 1;
    // p0: quadrant (M0,N0), read A-half0; stage B1(t+1) into other buf
    PHASE8(0, 0, 1, { if (t + 1 < NT) stB(nxt, 1, t + 1); }, {});
    // p1: quadrant (M0,N1), reuse A; stage A0(t+2) (region died at p0)
    PHASE8(0, 1, 0, { if (t + 2 < NT) stA(cur, 0, t + 2); }, {});
    // p2: quadrant (M1,N0), read A-half1
    PHASE8(1, 0, 1, {}, {});
    // p3: quadrant (M1,N1); stage B0(t+2)+A1(t+2) (died at p2); boundary wait
    PHASE8(1, 1, 0,
           { if (t + 2 < NT) { stB(cur, 0, t + 2); stA(cur, 1, t + 2); } },
           { if (t < NT - 1) {
               if (t == NT - 2) asm volatile("s_waitcnt vmcnt(0)" ::: "memory");
               else             asm volatile("s_waitcnt vmcnt(6)" ::: "memory");
             } });
  }

  // epilogue: C/D layout col=lane&15, row=(lane>>4)*4+reg
  const int col = lane & 15, rb = (lane >> 4) * 4;
#pragma unroll
  for (int mh = 0; mh < 2; mh++)
#pragma unroll
    for (int nh = 0; nh < 2; nh++)
#pragma unroll
      for (int mf = 0; mf < 4; mf++)
#pragma unroll
        for (int nf = 0; nf < 2; nf++) {
          const int gm = m0 + mh * 128 + wq * 64 + mf * 16 + rb;
          const int gn = n0 + nh * 128 + wn * 32 + nf * 16 + col;
          const float bv = bias[gn];
#pragma unroll
          for (int r = 0; r < 4; r++)
            Cout[(size_t)(gm + r) * N + gn] = (bf16_t)(acc[mh][nh][mf][nf][r] + bv);
        }
}

// ---------------- GEMM (proj): C[M][N] = A[M][K] * Bt[N][K]^T + bias ----------
// 128x128 tile, BK=32, 4 waves 2x2; double-buffered LDS, issue-early staging.
template <int OUT_BF16>
__global__ __launch_bounds__(256) void k_gemm_bt(const bf16_t* __restrict__ A,
                                                 const bf16_t* __restrict__ Bt,
                                                 const float* __restrict__ bias,
                                                 void* __restrict__ Cout,
                                                 int M, int N, int K) {
  __shared__ __align__(16) bf16_t lsA[2][128 * 32];
  __shared__ __align__(16) bf16_t lsB[2][128 * 32];
  const int tid  = threadIdx.x;
  const int lane = tid & 63;
  const int wid  = tid >> 6;
  const int wr   = wid >> 1, wc = wid & 1;
  const int m0 = blockIdx.x * 128, n0 = blockIdx.y * 128;

  const int srow = tid >> 2;
  const int scol = (tid & 3) * 8;
  const bf16_t* Ap = A  + (size_t)(m0 + srow) * K + scol;
  const bf16_t* Bp = Bt + (size_t)(n0 + srow) * K + scol;
  const int wbase = (tid & ~63) * 8;

  f32x4 acc[4][4];
#pragma unroll
  for (int i = 0; i < 4; i++)
#pragma unroll
    for (int j = 0; j < 4; j++) acc[i][j] = (f32x4){0.f, 0.f, 0.f, 0.f};

  const int fr = lane & 15;
  const int kb = (lane >> 4) * 8;

  auto stage = [&](int buf, int k0) {
    GLOAD_LDS16(Ap + k0,                  &lsA[buf][wbase]);
    GLOAD_LDS16(Ap + (size_t)64 * K + k0, &lsA[buf][2048 + wbase]);
    GLOAD_LDS16(Bp + k0,                  &lsB[buf][wbase]);
    GLOAD_LDS16(Bp + (size_t)64 * K + k0, &lsB[buf][2048 + wbase]);
  };

  stage(0, 0);
  __syncthreads();
  const int nk = K >> 5;
  for (int kt = 0; kt < nk; kt++) {
    const int cur = kt & 1;
    if (kt + 1 < nk) stage(cur ^ 1, (kt + 1) * 32);
    bf16x8 af[4], bfr[4];
#pragma unroll
    for (int mf = 0; mf < 4; mf++)
      af[mf] = *(const bf16x8*)&lsA[cur][(wr * 64 + mf * 16 + fr) * 32 + kb];
#pragma unroll
    for (int nf = 0; nf < 4; nf++)
      bfr[nf] = *(const bf16x8*)&lsB[cur][(wc * 64 + nf * 16 + fr) * 32 + kb];
#pragma unroll
    for (int mf = 0; mf < 4; mf++)
#pragma unroll
      for (int nf = 0; nf < 4; nf++)
        acc[mf][nf] = MFMA16(af[mf], bfr[nf], acc[mf][nf]);
    __syncthreads();
  }

  const int col = lane & 15, rb = (lane >> 4) * 4;
#pragma unroll
  for (int mf = 0; mf < 4; mf++) {
#pragma unroll
    for (int nf = 0; nf < 4; nf++) {
      const int gm = m0 + wr * 64 + mf * 16 + rb;
      const int gn = n0 + wc * 64 + nf * 16 + col;
      const float bv = bias[gn];
#pragma unroll
      for (int r = 0; r < 4; r++) {
        float v = acc[mf][nf][r] + bv;
        if (OUT_BF16)
          ((bf16_t*)Cout)[(size_t)(gm + r) * N + gn] = (bf16_t)v;
        else
          ((float*)Cout)[(size_t)(gm + r) * N + gn] = v;
      }
    }
  }
}

// ---------------- causal flash attention (round-5 best: 82.8 us) ----------------
__global__ __launch_bounds__(256, 2) void k_attn(const bf16_t* __restrict__ qkv,
                                                 const bf16_t* __restrict__ vt,
                                                 bf16_t* __restrict__ attout) {
  __shared__ __align__(16) bf16_t lsK[3][64 * 64];
  __shared__ __align__(16) bf16_t lsV[3][64 * 64];
  const int tid = threadIdx.x, lane = tid & 63, w = tid >> 6;
  const int blk = blockIdx.x;
  const int xcd = blk & 7, idx = blk >> 3;
  const int bh  = xcd * 8 + (idx & 7);
  const int qsb = 7 - (idx >> 3);
  const int b = bh >> 4, h = bh & 15;
  const bf16_t* Qb  = qkv + (size_t)b * SEQ * QKV_LD + h * HDIM;
  const bf16_t* Kb  = Qb + NX;
  const bf16_t* Vtb = vt + (size_t)bh * HDIM * SEQ;

  const int fr = lane & 15, g2 = lane >> 4;
  const int kb8 = g2 * 8;
  const int permA = (fr & 3) + 8 * (fr >> 2);

  auto stage = [&](int buf, int kv0) {
#pragma unroll
    for (int s = 0; s < 2; s++) {
      const int i = w * 128 + s * 64 + lane;
      const int row = i >> 3, slot = i & 7;
      const int sk = (row & 3) | (((row >> 3) & 1) << 2);
      GLOAD_LDS16(Kb + (size_t)(kv0 + row) * QKV_LD + ((slot ^ sk) << 3),
                  &lsK[buf][(w * 128 + s * 64) * 8]);
      GLOAD_LDS16(Vtb + (size_t)row * SEQ + kv0 + ((slot ^ (row & 7)) << 3),
                  &lsV[buf][(w * 128 + s * 64) * 8]);
    }
  };

  const int wb = qsb * 256 + w * 64;
  const int kv_last = wb;
  const int nst = qsb * 4 + 4;

  bf16x8 bq[4][2];
#pragma unroll
  for (int g = 0; g < 4; g++)
#pragma unroll
    for (int kf = 0; kf < 2; kf++) {
      bf16x8 t = *(const bf16x8*)&Qb[(size_t)(wb + g * 16 + fr) * QKV_LD + kf * 32 + kb8];
#pragma unroll
      for (int jj = 0; jj < 8; jj++) t[jj] = (bf16_t)((float)t[jj] * 0.1803368801f);
      bq[g][kf] = t;
    }

  float l_run[4] = {0.f, 0.f, 0.f, 0.f};
  f32x4 o[4][4];
#pragma unroll
  for (int g = 0; g < 4; g++)
#pragma unroll
    for (int d = 0; d < 4; d++) o[g][d] = (f32x4){0.f, 0.f, 0.f, 0.f};

  stage(0, 0);
  stage(1, 64);
  asm volatile("s_waitcnt vmcnt(4)" ::: "memory");
  __builtin_amdgcn_s_barrier();

  for (int st = 0; st < nst; st++) {
    const int kv0 = st * 64;
    const int cur = st % 3;
    if (st + 2 < nst) stage((st + 2) % 3, (st + 2) * 64);
    if (kv0 <= kv_last) {
      bf16x8 ak[2][2][2];
#pragma unroll
      for (int sub = 0; sub < 2; sub++)
#pragma unroll
        for (int ab = 0; ab < 2; ab++)
#pragma unroll
          for (int kf = 0; kf < 2; kf++) {
            const int row = sub * 32 + ab * 4 + permA;
            const int sk = (row & 3) | (((row >> 3) & 1) << 2);
            const int c = kf * 4 + g2;
            ak[sub][ab][kf] = *(const bf16x8*)&lsK[cur][row * 64 + ((c ^ sk) << 3)];
          }
      bf16x8 vbf[4][2];
#pragma unroll
      for (int df = 0; df < 4; df++)
#pragma unroll
        for (int hh = 0; hh < 2; hh++) {
          const int row = df * 16 + fr;
          const int c = hh * 4 + g2;
          vbf[df][hh] = *(const bf16x8*)&lsV[cur][row * 64 + ((c ^ (row & 7)) << 3)];
        }
      const int masked = (kv0 == kv_last);
#pragma unroll
      for (int g = 0; g < 4; g++) {
        f32x4 sAB[2][2];
        __builtin_amdgcn_s_setprio(1);
#pragma unroll
        for (int sub = 0; sub < 2; sub++)
#pragma unroll
          for (int ab = 0; ab < 2; ab++) {
            f32x4 s0 = (f32x4){0.f, 0.f, 0.f, 0.f};
            s0 = MFMA16(ak[sub][ab][0], bq[g][0], s0);
            s0 = MFMA16(ak[sub][ab][1], bq[g][1], s0);
            sAB[sub][ab] = s0;
          }
        __builtin_amdgcn_s_setprio(0);
        float sv[16];
#pragma unroll
        for (int sub = 0; sub < 2; sub++)
#pragma unroll
          for (int r = 0; r < 4; r++) {
            sv[sub * 8 + r]     = sAB[sub][0][r];
            sv[sub * 8 + 4 + r] = sAB[sub][1][r];
          }
        if (masked) {
          const int q_abs = wb + g * 16 + fr;
#pragma unroll
          for (int sub = 0; sub < 2; sub++)
#pragma unroll
            for (int r = 0; r < 4; r++) {
              if (kv0 + sub * 32 + g2 * 8 + r     > q_abs) sv[sub * 8 + r]     = -1e30f;
              if (kv0 + sub * 32 + g2 * 8 + 4 + r > q_abs) sv[sub * 8 + 4 + r] = -1e30f;
            }
        }
        float tsum = 0.f;
        bf16_t pb[16];
#pragma unroll
        for (int jj = 0; jj < 16; jj++) {
          float pv = exp2f(sv[jj]);
          tsum += pv;
          pb[jj] = (bf16_t)pv;
        }
        l_run[g] += tsum;
        bf16x8 pa0, pa1;
#pragma unroll
        for (int jj = 0; jj < 8; jj++) { pa0[jj] = pb[jj]; pa1[jj] = pb[8 + jj]; }
        __builtin_amdgcn_s_setprio(1);
#pragma unroll
        for (int df = 0; df < 4; df++) {
          o[g][df] = MFMA16(pa0, vbf[df][0], o[g][df]);
          o[g][df] = MFMA16(pa1, vbf[df][1], o[g][df]);
        }
        __builtin_amdgcn_s_setprio(0);
      }
    }
    if (st + 1 < nst) {
      if (st + 2 < nst) WAIT_VM4_BAR(); else WAIT_VM0_BAR();
    }
  }

#pragma unroll
  for (int g = 0; g < 4; g++) {
    float lt = l_run[g];
    lt += __shfl_xor(lt, 16);
    lt += __shfl_xor(lt, 32);
    const float inv = 1.f / lt;
#pragma unroll
    for (int r = 0; r < 4; r++) {
      const float iv = __shfl(inv, g2 * 4 + r);
      const int tok = b * SEQ + wb + g * 16 + g2 * 4 + r;
#pragma unroll
      for (int df = 0; df < 4; df++)
        attout[(size_t)tok * NX + h * HDIM + df * 16 + fr] = (bf16_t)(o[g][df][r] * iv);
    }
  }
}

// ---------------- launch ----------------
extern "C" void kernel_launch(void* const* d_in, const int* in_sizes, int n_in,
                              void* d_out, int out_size, void* d_ws, size_t ws_size,
                              hipStream_t stream) {
  const float* x      = (const float*)d_in[0];
  const float* w_attn = (const float*)d_in[1];
  const float* b_attn = (const float*)d_in[2];
  const float* w_proj = (const float*)d_in[3];
  const float* b_proj = (const float*)d_in[4];

  char* ws = (char*)d_ws;
  bf16_t* xb  = (bf16_t*)ws;                   // [0,16) MiB, reused as att
  bf16_t* qkv = (bf16_t*)(ws + (16u << 20));   // [16,64) MiB
  bf16_t* wab = (bf16_t*)(ws + (64u << 20));   // [64,70) MiB, dead after QKV GEMM
  bf16_t* vt  = (bf16_t*)(ws + (64u << 20));   // [64,80) MiB (reuses wab region)
  bf16_t* wpb = (bf16_t*)(ws + (80u << 20));   // [80,82) MiB
  bf16_t* att = xb;

  k_cast_bf16<<<2048, 256, 0, stream>>>(x, xb, NTOK * NX / 4);
  k_transpose_cast<<<dim3(NX / 32, (3 * NX) / 32), 256, 0, stream>>>(w_attn, wab, NX, 3 * NX);
  k_gemm8<<<dim3(NTOK / 256, (3 * NX) / 256), 512, 0, stream>>>(
      xb, wab, b_attn, qkv, NTOK, 3 * NX, NX);
  // xb and wab dead from here
  k_vtrans<<<dim3(SEQ / 32, HDIM / 32, BATCH * NHEAD), 256, 0, stream>>>(qkv, vt);
  k_transpose_cast<<<dim3(NX / 32, NX / 32), 256, 0, stream>>>(w_proj, wpb, NX, NX);
  k_attn<<<BATCH * NHEAD * 8, 256, 0, stream>>>(qkv, vt, att);
  k_gemm_bt<0><<<dim3(NTOK / 128, NX / 128), 256, 0, stream>>>(
      att, wpb, b_proj, d_out, NTOK, NX, NX);
}

// Round 10
// 186.499 us; speedup vs baseline: 1.1057x; 1.0647x over previous
//
#include <hip/hip_runtime.h>
#include <stdint.h>

#define BATCH 4
#define SEQ 2048
#define NX 1024
#define NHEAD 16
#define HDIM 64
#define NTOK (BATCH * SEQ)   // 8192
#define QKV_LD (3 * NX)      // 3072

typedef __bf16 bf16_t;
typedef __bf16 bf16x8 __attribute__((ext_vector_type(8)));
typedef __bf16 bf16x4 __attribute__((ext_vector_type(4)));
typedef float  f32x4  __attribute__((ext_vector_type(4)));

#define GLOAD_LDS16(g, l) __builtin_amdgcn_global_load_lds( \
    (const __attribute__((address_space(1))) void*)(g),     \
    (__attribute__((address_space(3))) void*)(l), 16, 0, 0)

#define MFMA16(a, b, c) __builtin_amdgcn_mfma_f32_16x16x32_bf16((a), (b), (c), 0, 0, 0)

#define WAIT_VM4_BAR() do { \
    asm volatile("s_waitcnt vmcnt(4) lgkmcnt(0)" ::: "memory"); \
    __builtin_amdgcn_s_barrier(); } while (0)
#define WAIT_VM0_BAR() do { \
    asm volatile("s_waitcnt vmcnt(0) lgkmcnt(0)" ::: "memory"); \
    __builtin_amdgcn_s_barrier(); } while (0)

// V-stripe mapping: V(b,h,d,s) lives in the (otherwise dead) V third of the
// qkv buffer, TRANSPOSED: elem = b*SEQ*QKV_LD + ((h*64+d)*2 + (s>>10))*QKV_LD
//                               + 2048 + (s&1023)
// Writer (QKV GEMM epilogue) and reader (attn stage) both use this mapping.

// ---------------- cast f32 -> bf16 (vectorized) ----------------
__global__ __launch_bounds__(256) void k_cast_bf16(const float* __restrict__ in,
                                                   bf16_t* __restrict__ out, int n4) {
  int stride = gridDim.x * blockDim.x;
  for (int i = blockIdx.x * blockDim.x + threadIdx.x; i < n4; i += stride) {
    f32x4 v = ((const f32x4*)in)[i];
    bf16x4 o;
    o[0] = (bf16_t)v[0]; o[1] = (bf16_t)v[1];
    o[2] = (bf16_t)v[2]; o[3] = (bf16_t)v[3];
    ((bf16x4*)out)[i] = o;
  }
}

// ---------------- transpose + cast: in[K][N] f32 -> out[N][K] bf16 ----------------
__global__ __launch_bounds__(256) void k_transpose_cast(const float* __restrict__ in,
                                                        bf16_t* __restrict__ out,
                                                        int K, int N) {
  __shared__ float tile[32][33];
  const int kb = blockIdx.x * 32, nb = blockIdx.y * 32;
  const int tx = threadIdx.x & 31;
  const int ty = (threadIdx.x >> 5) * 4;
#pragma unroll
  for (int i = 0; i < 4; i++)
    tile[ty + i][tx] = in[(size_t)(kb + ty + i) * N + nb + tx];
  __syncthreads();
#pragma unroll
  for (int i = 0; i < 4; i++)
    out[(size_t)(nb + ty + i) * K + kb + tx] = (bf16_t)tile[tx][ty + i];
}

// ---------------- QKV GEMM: qkv[M][3072] = A[M][K] * Bt^T + bias --------------
// 128x128 tile, BK=32, 4 waves 2x2; double-buffered LDS, issue-early staging
// (r5 measured-best structure). V-blocks (n0>=2048) write TRANSPOSED into the
// qkv V-stripe via an LDS transpose tile instead of the natural C location.
__global__ __launch_bounds__(256) void k_gemm_qkv(const bf16_t* __restrict__ A,
                                                  const bf16_t* __restrict__ Bt,
                                                  const float* __restrict__ bias,
                                                  bf16_t* __restrict__ qkv,
                                                  int M, int N, int K) {
  __shared__ __align__(16) bf16_t lsPool[2][2][128 * 32];   // 32 KB
  auto* lsA = lsPool[0];
  auto* lsB = lsPool[1];
  const int tid  = threadIdx.x;
  const int lane = tid & 63;
  const int wid  = tid >> 6;
  const int wr   = wid >> 1, wc = wid & 1;
  const int m0 = blockIdx.x * 128, n0 = blockIdx.y * 128;

  const int srow = tid >> 2;
  const int scol = (tid & 3) * 8;
  const bf16_t* Ap = A  + (size_t)(m0 + srow) * K + scol;
  const bf16_t* Bp = Bt + (size_t)(n0 + srow) * K + scol;
  const int wbase = (tid & ~63) * 8;

  f32x4 acc[4][4];
#pragma unroll
  for (int i = 0; i < 4; i++)
#pragma unroll
    for (int j = 0; j < 4; j++) acc[i][j] = (f32x4){0.f, 0.f, 0.f, 0.f};

  const int fr = lane & 15;
  const int kb = (lane >> 4) * 8;

  auto stage = [&](int buf, int k0) {
    GLOAD_LDS16(Ap + k0,                  &lsA[buf][wbase]);
    GLOAD_LDS16(Ap + (size_t)64 * K + k0, &lsA[buf][2048 + wbase]);
    GLOAD_LDS16(Bp + k0,                  &lsB[buf][wbase]);
    GLOAD_LDS16(Bp + (size_t)64 * K + k0, &lsB[buf][2048 + wbase]);
  };

  stage(0, 0);
  __syncthreads();
  const int nk = K >> 5;
  for (int kt = 0; kt < nk; kt++) {
    const int cur = kt & 1;
    if (kt + 1 < nk) stage(cur ^ 1, (kt + 1) * 32);
    bf16x8 af[4], bfr[4];
#pragma unroll
    for (int mf = 0; mf < 4; mf++)
      af[mf] = *(const bf16x8*)&lsA[cur][(wr * 64 + mf * 16 + fr) * 32 + kb];
#pragma unroll
    for (int nf = 0; nf < 4; nf++)
      bfr[nf] = *(const bf16x8*)&lsB[cur][(wc * 64 + nf * 16 + fr) * 32 + kb];
#pragma unroll
    for (int mf = 0; mf < 4; mf++)
#pragma unroll
      for (int nf = 0; nf < 4; nf++)
        acc[mf][nf] = MFMA16(af[mf], bfr[nf], acc[mf][nf]);
    __syncthreads();
  }

  // C/D layout: col = lane&15, row = (lane>>4)*4 + reg
  const int col = lane & 15, rb = (lane >> 4) * 4;

  if (n0 < 2 * NX) {
    // Q/K block: normal write
#pragma unroll
    for (int mf = 0; mf < 4; mf++)
#pragma unroll
      for (int nf = 0; nf < 4; nf++) {
        const int gm = m0 + wr * 64 + mf * 16 + rb;
        const int gn = n0 + wc * 64 + nf * 16 + col;
        const float bv = bias[gn];
#pragma unroll
        for (int r = 0; r < 4; r++)
          qkv[(size_t)(gm + r) * QKV_LD + gn] = (bf16_t)(acc[mf][nf][r] + bv);
      }
  } else {
    // V block: transpose via LDS ([64][136] bf16 = 17 KB, aliased on lsPool)
    bf16_t* lt = &lsPool[0][0][0];
    const int bb  = m0 >> 11;            // batch
    const int m0s = m0 & 2047;           // token offset within batch
    const int rr = tid >> 4, cc = tid & 15;
#pragma unroll
    for (int p = 0; p < 2; p++) {        // two 64-col halves (= wc halves)
      __syncthreads();
      if (wc == p) {
#pragma unroll
        for (int mf = 0; mf < 4; mf++)
#pragma unroll
          for (int nf = 0; nf < 4; nf++) {
            const float bv = bias[n0 + wc * 64 + nf * 16 + col];
            bf16x4 v4;
#pragma unroll
            for (int r = 0; r < 4; r++) v4[r] = (bf16_t)(acc[mf][nf][r] + bv);
            *(bf16x4*)&lt[(nf * 16 + col) * 136 + wr * 64 + mf * 16 + rb] = v4;
          }
      }
      __syncthreads();
      const int hh = ((n0 - 2 * NX) >> 6) + p;   // head index within batch
#pragma unroll
      for (int it = 0; it < 4; it++) {
        const int nn = it * 16 + rr;             // d within head
        bf16x8 v = *(const bf16x8*)&lt[nn * 136 + cc * 8];
        const size_t dst = (size_t)bb * SEQ * QKV_LD +
                           (size_t)((hh * 64 + nn) * 2 + (m0s >> 10)) * QKV_LD +
                           2 * NX + (m0s & 1023) + cc * 8;
        *(bf16x8*)&qkv[dst] = v;
      }
    }
  }
}

// ---------------- GEMM (proj): C[M][N] = A[M][K] * Bt[N][K]^T + bias, f32 out --
__global__ __launch_bounds__(256) void k_gemm_bt(const bf16_t* __restrict__ A,
                                                 const bf16_t* __restrict__ Bt,
                                                 const float* __restrict__ bias,
                                                 float* __restrict__ Cout,
                                                 int M, int N, int K) {
  __shared__ __align__(16) bf16_t lsA[2][128 * 32];
  __shared__ __align__(16) bf16_t lsB[2][128 * 32];
  const int tid  = threadIdx.x;
  const int lane = tid & 63;
  const int wid  = tid >> 6;
  const int wr   = wid >> 1, wc = wid & 1;
  const int m0 = blockIdx.x * 128, n0 = blockIdx.y * 128;

  const int srow = tid >> 2;
  const int scol = (tid & 3) * 8;
  const bf16_t* Ap = A  + (size_t)(m0 + srow) * K + scol;
  const bf16_t* Bp = Bt + (size_t)(n0 + srow) * K + scol;
  const int wbase = (tid & ~63) * 8;

  f32x4 acc[4][4];
#pragma unroll
  for (int i = 0; i < 4; i++)
#pragma unroll
    for (int j = 0; j < 4; j++) acc[i][j] = (f32x4){0.f, 0.f, 0.f, 0.f};

  const int fr = lane & 15;
  const int kb = (lane >> 4) * 8;

  auto stage = [&](int buf, int k0) {
    GLOAD_LDS16(Ap + k0,                  &lsA[buf][wbase]);
    GLOAD_LDS16(Ap + (size_t)64 * K + k0, &lsA[buf][2048 + wbase]);
    GLOAD_LDS16(Bp + k0,                  &lsB[buf][wbase]);
    GLOAD_LDS16(Bp + (size_t)64 * K + k0, &lsB[buf][2048 + wbase]);
  };

  stage(0, 0);
  __syncthreads();
  const int nk = K >> 5;
  for (int kt = 0; kt < nk; kt++) {
    const int cur = kt & 1;
    if (kt + 1 < nk) stage(cur ^ 1, (kt + 1) * 32);
    bf16x8 af[4], bfr[4];
#pragma unroll
    for (int mf = 0; mf < 4; mf++)
      af[mf] = *(const bf16x8*)&lsA[cur][(wr * 64 + mf * 16 + fr) * 32 + kb];
#pragma unroll
    for (int nf = 0; nf < 4; nf++)
      bfr[nf] = *(const bf16x8*)&lsB[cur][(wc * 64 + nf * 16 + fr) * 32 + kb];
#pragma unroll
    for (int mf = 0; mf < 4; mf++)
#pragma unroll
      for (int nf = 0; nf < 4; nf++)
        acc[mf][nf] = MFMA16(af[mf], bfr[nf], acc[mf][nf]);
    __syncthreads();
  }

  const int col = lane & 15, rb = (lane >> 4) * 4;
#pragma unroll
  for (int mf = 0; mf < 4; mf++) {
#pragma unroll
    for (int nf = 0; nf < 4; nf++) {
      const int gm = m0 + wr * 64 + mf * 16 + rb;
      const int gn = n0 + wc * 64 + nf * 16 + col;
      const float bv = bias[gn];
#pragma unroll
      for (int r = 0; r < 4; r++)
        Cout[(size_t)(gm + r) * N + gn] = acc[mf][nf][r] + bv;
    }
  }
}

// ---------------- causal flash attention (r5 best: 82.8 us) ----------------
// 4 waves/block, 64 q-rows per wave, KVBLK=64; 3-buffer LDS, depth-2 prefetch,
// counted vmcnt + raw barrier; swapped QK^T + permuted K rows; no-max softmax.
// V read from the qkv V-stripe via the transposed mapping (see top).
__global__ __launch_bounds__(256, 2) void k_attn(const bf16_t* __restrict__ qkv,
                                                 bf16_t* __restrict__ attout) {
  __shared__ __align__(16) bf16_t lsK[3][64 * 64];
  __shared__ __align__(16) bf16_t lsV[3][64 * 64];
  const int tid = threadIdx.x, lane = tid & 63, w = tid >> 6;
  const int blk = blockIdx.x;
  const int xcd = blk & 7, idx = blk >> 3;
  const int bh  = xcd * 8 + (idx & 7);
  const int qsb = 7 - (idx >> 3);
  const int b = bh >> 4, h = bh & 15;
  const bf16_t* Qb = qkv + (size_t)b * SEQ * QKV_LD + h * HDIM;
  const bf16_t* Kb = Qb + NX;
  const bf16_t* Vs = qkv + (size_t)b * SEQ * QKV_LD + 2 * NX;  // V-stripe base

  const int fr = lane & 15, g2 = lane >> 4;
  const int kb8 = g2 * 8;
  const int permA = (fr & 3) + 8 * (fr >> 2);

  auto stage = [&](int buf, int kv0) {
#pragma unroll
    for (int s = 0; s < 2; s++) {
      const int i = w * 128 + s * 64 + lane;
      const int row = i >> 3, slot = i & 7;
      const int sk = (row & 3) | (((row >> 3) & 1) << 2);
      GLOAD_LDS16(Kb + (size_t)(kv0 + row) * QKV_LD + ((slot ^ sk) << 3),
                  &lsK[buf][(w * 128 + s * 64) * 8]);
      GLOAD_LDS16(Vs + (size_t)((h * 64 + row) * 2 + (kv0 >> 10)) * QKV_LD +
                      (kv0 & 1023) + ((slot ^ (row & 7)) << 3),
                  &lsV[buf][(w * 128 + s * 64) * 8]);
    }
  };

  const int wb = qsb * 256 + w * 64;
  const int kv_last = wb;
  const int nst = qsb * 4 + 4;

  bf16x8 bq[4][2];
#pragma unroll
  for (int g = 0; g < 4; g++)
#pragma unroll
    for (int kf = 0; kf < 2; kf++) {
      bf16x8 t = *(const bf16x8*)&Qb[(size_t)(wb + g * 16 + fr) * QKV_LD + kf * 32 + kb8];
#pragma unroll
      for (int jj = 0; jj < 8; jj++) t[jj] = (bf16_t)((float)t[jj] * 0.1803368801f);
      bq[g][kf] = t;
    }

  float l_run[4] = {0.f, 0.f, 0.f, 0.f};
  f32x4 o[4][4];
#pragma unroll
  for (int g = 0; g < 4; g++)
#pragma unroll
    for (int d = 0; d < 4; d++) o[g][d] = (f32x4){0.f, 0.f, 0.f, 0.f};

  stage(0, 0);
  stage(1, 64);
  asm volatile("s_waitcnt vmcnt(4)" ::: "memory");
  __builtin_amdgcn_s_barrier();

  for (int st = 0; st < nst; st++) {
    const int kv0 = st * 64;
    const int cur = st % 3;
    if (st + 2 < nst) stage((st + 2) % 3, (st + 2) * 64);
    if (kv0 <= kv_last) {
      bf16x8 ak[2][2][2];
#pragma unroll
      for (int sub = 0; sub < 2; sub++)
#pragma unroll
        for (int ab = 0; ab < 2; ab++)
#pragma unroll
          for (int kf = 0; kf < 2; kf++) {
            const int row = sub * 32 + ab * 4 + permA;
            const int sk = (row & 3) | (((row >> 3) & 1) << 2);
            const int c = kf * 4 + g2;
            ak[sub][ab][kf] = *(const bf16x8*)&lsK[cur][row * 64 + ((c ^ sk) << 3)];
          }
      bf16x8 vbf[4][2];
#pragma unroll
      for (int df = 0; df < 4; df++)
#pragma unroll
        for (int hh = 0; hh < 2; hh++) {
          const int row = df * 16 + fr;
          const int c = hh * 4 + g2;
          vbf[df][hh] = *(const bf16x8*)&lsV[cur][row * 64 + ((c ^ (row & 7)) << 3)];
        }
      const int masked = (kv0 == kv_last);
#pragma unroll
      for (int g = 0; g < 4; g++) {
        f32x4 sAB[2][2];
        __builtin_amdgcn_s_setprio(1);
#pragma unroll
        for (int sub = 0; sub < 2; sub++)
#pragma unroll
          for (int ab = 0; ab < 2; ab++) {
            f32x4 s0 = (f32x4){0.f, 0.f, 0.f, 0.f};
            s0 = MFMA16(ak[sub][ab][0], bq[g][0], s0);
            s0 = MFMA16(ak[sub][ab][1], bq[g][1], s0);
            sAB[sub][ab] = s0;
          }
        __builtin_amdgcn_s_setprio(0);
        float sv[16];
#pragma unroll
        for (int sub = 0; sub < 2; sub++)
#pragma unroll
          for (int r = 0; r < 4; r++) {
            sv[sub * 8 + r]     = sAB[sub][0][r];
            sv[sub * 8 + 4 + r] = sAB[sub][1][r];
          }
        if (masked) {
          const int q_abs = wb + g * 16 + fr;
#pragma unroll
          for (int sub = 0; sub < 2; sub++)
#pragma unroll
            for (int r = 0; r < 4; r++) {
              if (kv0 + sub * 32 + g2 * 8 + r     > q_abs) sv[sub * 8 + r]     = -1e30f;
              if (kv0 + sub * 32 + g2 * 8 + 4 + r > q_abs) sv[sub * 8 + 4 + r] = -1e30f;
            }
        }
        float tsum = 0.f;
        bf16_t pb[16];
#pragma unroll
        for (int jj = 0; jj < 16; jj++) {
          float pv = exp2f(sv[jj]);
          tsum += pv;
          pb[jj] = (bf16_t)pv;
        }
        l_run[g] += tsum;
        bf16x8 pa0, pa1;
#pragma unroll
        for (int jj = 0; jj < 8; jj++) { pa0[jj] = pb[jj]; pa1[jj] = pb[8 + jj]; }
        __builtin_amdgcn_s_setprio(1);
#pragma unroll
        for (int df = 0; df < 4; df++) {
          o[g][df] = MFMA16(pa0, vbf[df][0], o[g][df]);
          o[g][df] = MFMA16(pa1, vbf[df][1], o[g][df]);
        }
        __builtin_amdgcn_s_setprio(0);
      }
    }
    if (st + 1 < nst) {
      if (st + 2 < nst) WAIT_VM4_BAR(); else WAIT_VM0_BAR();
    }
  }

#pragma unroll
  for (int g = 0; g < 4; g++) {
    float lt = l_run[g];
    lt += __shfl_xor(lt, 16);
    lt += __shfl_xor(lt, 32);
    const float inv = 1.f / lt;
#pragma unroll
    for (int r = 0; r < 4; r++) {
      const float iv = __shfl(inv, g2 * 4 + r);
      const int tok = b * SEQ + wb + g * 16 + g2 * 4 + r;
#pragma unroll
      for (int df = 0; df < 4; df++)
        attout[(size_t)tok * NX + h * HDIM + df * 16 + fr] = (bf16_t)(o[g][df][r] * iv);
    }
  }
}

// ---------------- launch ----------------
extern "C" void kernel_launch(void* const* d_in, const int* in_sizes, int n_in,
                              void* d_out, int out_size, void* d_ws, size_t ws_size,
                              hipStream_t stream) {
  const float* x      = (const float*)d_in[0];
  const float* w_attn = (const float*)d_in[1];
  const float* b_attn = (const float*)d_in[2];
  const float* w_proj = (const float*)d_in[3];
  const float* b_proj = (const float*)d_in[4];

  char* ws = (char*)d_ws;
  bf16_t* xb  = (bf16_t*)ws;                   // [0,16) MiB, reused as att
  bf16_t* qkv = (bf16_t*)(ws + (16u << 20));   // [16,64) MiB (V third = vt stripe)
  bf16_t* wab = (bf16_t*)(ws + (64u << 20));   // [64,70) MiB, dead after QKV GEMM
  bf16_t* wpb = (bf16_t*)(ws + (70u << 20));   // [70,72) MiB
  bf16_t* att = xb;

  k_cast_bf16<<<2048, 256, 0, stream>>>(x, xb, NTOK * NX / 4);
  k_transpose_cast<<<dim3(NX / 32, (3 * NX) / 32), 256, 0, stream>>>(w_attn, wab, NX, 3 * NX);
  k_gemm_qkv<<<dim3(NTOK / 128, (3 * NX) / 128), 256, 0, stream>>>(
      xb, wab, b_attn, qkv, NTOK, 3 * NX, NX);
  // xb and wab dead from here; V already transposed into the qkv stripe
  k_transpose_cast<<<dim3(NX / 32, NX / 32), 256, 0, stream>>>(w_proj, wpb, NX, NX);
  k_attn<<<BATCH * NHEAD * 8, 256, 0, stream>>>(qkv, att);
  k_gemm_bt<<<dim3(NTOK / 128, NX / 128), 256, 0, stream>>>(
      att, wpb, b_proj, (float*)d_out, NTOK, NX, NX);
}